// Round 2
// baseline (137.721 us; speedup 1.0000x reference)
//
#include <hip/hip_runtime.h>
#include <math.h>

#define D 100
#define NEG_SLOPE 0.2f
#define CHUNK 32         // pairs per chunk; 2 lanes per pair (was 16 / 4 lanes)
#define ROWU 52          // uints per packed-f16 row, padded 50->52 for 16B align

// compiler-only memory barrier (validated R17: same-wave LDS is pipe-ordered,
// no lgkmcnt(0) drain needed; this only stops compiler reordering)
#define COMPILER_FENCE() asm volatile("" ::: "memory")

typedef _Float16 f16x2 __attribute__((ext_vector_type(2)));
union U32H2 { unsigned int u; f16x2 h; };

__device__ __forceinline__ unsigned int pkh2(float x, float y) {
    U32H2 c; c.h.x = (_Float16)x; c.h.y = (_Float16)y; return c.u;
}

// 2-wide f16 dot + fp32 accumulate: v_dot2_f32_f16
__device__ __forceinline__ float dot2u(unsigned int au, unsigned int xu, float acc) {
#if __has_builtin(__builtin_amdgcn_fdot2)
    U32H2 a, x; a.u = au; x.u = xu;
    return __builtin_amdgcn_fdot2(a.h, x.h, acc, false);
#else
    U32H2 a, x; a.u = au; x.u = xu;
    return acc + (float)a.h.x * (float)x.h.x + (float)a.h.y * (float)x.h.y;
#endif
}

// DPP cross-lane (VALU pipe).
template<int CTRL>
__device__ __forceinline__ float dppf(float x) {
    return __uint_as_float((unsigned)__builtin_amdgcn_update_dpp(
        0, (int)__float_as_uint(x), CTRL, 0xF, 0xF, true));
}
__device__ __forceinline__ float red16_max(float x) {
    x = fmaxf(x, dppf<0xB1>(x));    // quad_perm xor1
    x = fmaxf(x, dppf<0x4E>(x));    // quad_perm xor2
    x = fmaxf(x, dppf<0x124>(x));   // row_ror:4
    x = fmaxf(x, dppf<0x128>(x));   // row_ror:8
    return x;
}
__device__ __forceinline__ float red16_sum(float x) {
    x += dppf<0xB1>(x);
    x += dppf<0x4E>(x);
    x += dppf<0x124>(x);
    x += dppf<0x128>(x);
    return x;
}

// Fused prep: t < P: row_ptr boundary scatter; t < total25: fp32 -> f16 pack;
// t < n: zero the 2 pad uints (dims 100..103) so pad dots contribute 0.
__global__ void prep_kernel(const int* __restrict__ seg,
                            int* __restrict__ row_ptr,
                            const float* __restrict__ hidden,
                            unsigned int* __restrict__ hb,
                            int n, int P, int total25)
{
    int t = blockIdx.x * blockDim.x + threadIdx.x;
    if (t < P) {
        int s0 = seg[t];
        if (t == 0)
            for (int v = 0; v <= s0; v++) row_ptr[v] = 0;
        int s1 = (t + 1 < P) ? seg[t + 1] : n;
        for (int v = s0 + 1; v <= s1; v++) row_ptr[v] = t + 1;
    }
    if (t < total25) {
        int node = t / 25, k = t - node * 25;   // 25 float4-groups per row
        float4 f = ((const float4*)hidden)[t];
        *(uint2*)&hb[node * ROWU + 2 * k] =
            make_uint2(pkh2(f.x, f.y), pkh2(f.z, f.w));
    }
    if (t < n) {                                // zero pad uints 50,51
        *(uint2*)&hb[(size_t)t * ROWU + 50] = make_uint2(0u, 0u);
    }
}

// One wave per node. R2 restructure: CHUNK=32 with 2 lanes/pair — mean degree
// is ~26, so most nodes now run exactly ONE chunk iteration. This amortizes
// the per-chunk fixed tax (DPP max/sum trees, exps, rescale, fences, loop
// control) that dominated at CHUNK=16 (2.1 chunks/node avg); per-pair load
// instrs drop 16->13 and the shfl score-combine drops 2->1. Half-row split is
// asymmetric (q0: 7 uint4s = dims 0..55, q1: 6 uint4s = dims 56..99+pads) so
// ROWU stays 52 and every global/LDS access stays 16B-aligned. R1 lesson:
// register prefetch of next chunk was neutral (no next chunk to speak of,
// TLP already hides gather latency) — dropped.
__launch_bounds__(256, 8)
__global__ void gat_agg_kernel(const float* __restrict__ hidden,
                               const float* __restrict__ W,
                               const int* __restrict__ nbr,
                               const int* __restrict__ row_ptr,
                               const unsigned int* __restrict__ hb,
                               float* __restrict__ out,
                               int n, int P)
{
    __shared__ __align__(16) unsigned int s_hwp[4][ROWU];         // 0.83 KB
    __shared__ __align__(16) unsigned int s_rows[4][CHUNK][ROWU]; // 26.6 KB
    __shared__ __align__(16) float        s_e[4][CHUNK];          // 0.5 KB

    const int lane = threadIdx.x & 63;
    const int wid  = threadIdx.x >> 6;
    const int v    = blockIdx.x * 4 + wid;
    if (v >= n) return;          // wave-uniform exit; no block barriers used

    // hw[d] = hidden[v][d] * W[d] (fp32 product, f16-packed into LDS);
    // lanes 50,51 zero the pad uints so pad dots contribute 0.
    if (lane < ROWU) {
        unsigned int val = 0u;
        if (lane < 50) {
            float2 h2 = ((const float2*)(hidden + (long)v * D))[lane];
            float2 w2 = ((const float2*)W)[lane];
            val = pkh2(h2.x * w2.x, h2.y * w2.y);
        }
        s_hwp[wid][lane] = val;
    }
    COMPILER_FENCE();

    const int start = row_ptr[v];
    const int end   = row_ptr[v + 1];

    if (end <= start) {          // empty segment: zeros (matches reference)
        if (lane < D / 2)
            ((float2*)(out + (long)v * D))[lane] = make_float2(0.f, 0.f);
        return;
    }

    const int q  = lane >> 5;    // half: q0 = uint4s 0..6, q1 = uint4s 7..12
    const int jl = lane & 31;    // pair slot within the 32-chunk
    const int t0 = q * 7;        // uint4 index base

    const uint4* aq = ((const uint4*)&s_hwp[wid][0]) + t0;

    float m = -INFINITY, z = 0.f;
    float accx = 0.f, accy = 0.f;

    for (int c = start; c < end; c += CHUNK) {
        const int  cnt = min(CHUNK, end - c);
        const bool pv  = jl < cnt;

        // neighbor index: coalesced masked load. invalid lanes use row 0
        // (finite, in-bounds, L1-hot); e=0 masks them later.
        const int nbv = pv ? nbr[c + jl] : 0;

        // ---- Phase A: f16 half-row gather (q0: 7x16B, q1: 6x16B) ----
        const uint4* rp = ((const uint4*)hb) + nbv * (ROWU / 4) + t0;
        uint4 x0 = rp[0], x1 = rp[1], x2 = rp[2],
              x3 = rp[3], x4 = rp[4], x5 = rp[5];
        uint4 x6 = make_uint4(0u, 0u, 0u, 0u);
        if (q == 0) x6 = rp[6];

        // stage raw f16 half-rows to LDS (row = 13 uint4, 16B-aligned)
        uint4* dst = ((uint4*)&s_rows[wid][jl][0]) + t0;
        dst[0] = x0; dst[1] = x1; dst[2] = x2;
        dst[3] = x3; dst[4] = x4; dst[5] = x5;
        if (q == 0) dst[6] = x6;

        // dots: a-side broadcast-read from LDS (re-read per chunk keeps
        // VGPRs low; ~1.2 chunks/node makes the re-read cheap)
        float p0 = 0.f, p1 = 0.f, p2 = 0.f, p3 = 0.f;
        uint4 a;
        a = aq[0]; p0 = dot2u(a.x, x0.x, p0); p1 = dot2u(a.y, x0.y, p1);
                   p2 = dot2u(a.z, x0.z, p2); p3 = dot2u(a.w, x0.w, p3);
        a = aq[1]; p0 = dot2u(a.x, x1.x, p0); p1 = dot2u(a.y, x1.y, p1);
                   p2 = dot2u(a.z, x1.z, p2); p3 = dot2u(a.w, x1.w, p3);
        a = aq[2]; p0 = dot2u(a.x, x2.x, p0); p1 = dot2u(a.y, x2.y, p1);
                   p2 = dot2u(a.z, x2.z, p2); p3 = dot2u(a.w, x2.w, p3);
        a = aq[3]; p0 = dot2u(a.x, x3.x, p0); p1 = dot2u(a.y, x3.y, p1);
                   p2 = dot2u(a.z, x3.z, p2); p3 = dot2u(a.w, x3.w, p3);
        a = aq[4]; p0 = dot2u(a.x, x4.x, p0); p1 = dot2u(a.y, x4.y, p1);
                   p2 = dot2u(a.z, x4.z, p2); p3 = dot2u(a.w, x4.w, p3);
        a = aq[5]; p0 = dot2u(a.x, x5.x, p0); p1 = dot2u(a.y, x5.y, p1);
                   p2 = dot2u(a.z, x5.z, p2); p3 = dot2u(a.w, x5.w, p3);
        if (q == 0) {
            a = aq[6]; p0 = dot2u(a.x, x6.x, p0); p1 = dot2u(a.y, x6.y, p1);
                       p2 = dot2u(a.z, x6.z, p2); p3 = dot2u(a.w, x6.w, p3);
        }

        float part = (p0 + p1) + (p2 + p3);
        part += __shfl_xor(part, 32, 64);    // combine the two half-rows
        const float s = pv ? (part >= 0.f ? part : NEG_SLOPE * part)
                           : -INFINITY;

        // ---- online softmax over 32 pairs: DPP-16 tree + one shfl-16 ----
        float gmax = red16_max(s);
        gmax = fmaxf(gmax, __shfl_xor(gmax, 16, 64));
        const float m_new = fmaxf(m, gmax);
        const float scale = __expf(m - m_new);         // first chunk: 0
        const float e     = pv ? __expf(s - m_new) : 0.f;
        float gsum = red16_sum(e);
        gsum += __shfl_xor(gsum, 16, 64);
        z = z * scale + gsum;
        accx *= scale; accy *= scale;

        if (lane < CHUNK) s_e[wid][lane] = e;          // q0 lanes: jl == lane
        COMPILER_FENCE();        // order stores before phase-B reads (same wave)

        // ---- Phase B: lane-per-dim accumulate; v_fma_mix form ----
        const int cnt4 = (cnt + 3) & ~3;               // <= 32
        if (lane < D / 2) {
            for (int j0 = 0; j0 < cnt4; j0 += 4) {
                const float4 ev = *(const float4*)&s_e[wid][j0];  // broadcast
                U32H2 u0, u1, u2, u3;
                u0.u = s_rows[wid][j0    ][lane];
                u1.u = s_rows[wid][j0 + 1][lane];
                u2.u = s_rows[wid][j0 + 2][lane];
                u3.u = s_rows[wid][j0 + 3][lane];
                accx = fmaf((float)u0.h.x, ev.x, accx);
                accy = fmaf((float)u0.h.y, ev.x, accy);
                accx = fmaf((float)u1.h.x, ev.y, accx);
                accy = fmaf((float)u1.h.y, ev.y, accy);
                accx = fmaf((float)u2.h.x, ev.z, accx);
                accy = fmaf((float)u2.h.y, ev.z, accy);
                accx = fmaf((float)u3.h.x, ev.w, accx);
                accy = fmaf((float)u3.h.y, ev.w, accy);
            }
        }
        COMPILER_FENCE();        // phase-B reads before next chunk's stores
        m = m_new;
    }

    if (lane < D / 2) {
        const float inv = 1.f / z;
        ((float2*)(out + (long)v * D))[lane] = make_float2(accx * inv, accy * inv);
    }
}

extern "C" void kernel_launch(void* const* d_in, const int* in_sizes, int n_in,
                              void* d_out, int out_size, void* d_ws, size_t ws_size,
                              hipStream_t stream) {
    const float* hidden = (const float*)d_in[0];
    const float* W      = (const float*)d_in[1];
    const int*   seg    = (const int*)d_in[2];
    const int*   nbr    = (const int*)d_in[3];
    float*       out    = (float*)d_out;

    const int Ddim = in_sizes[1];           // 100
    const int n    = in_sizes[0] / Ddim;    // 50000
    const int P    = in_sizes[2];           // ~1.3M pairs

    // ws layout: row_ptr (n+1 ints) | hb (n*ROWU uints, 256B-aligned)
    int* row_ptr = (int*)d_ws;
    size_t hb_off = (((size_t)(n + 1) * 4) + 255) & ~(size_t)255;
    unsigned int* hb = (unsigned int*)((char*)d_ws + hb_off);

    const int total25 = n * 25;             // float4-groups in hidden
    const int tmax    = (P > total25) ? P : total25;
    hipLaunchKernelGGL(prep_kernel, dim3((tmax + 255) / 256), dim3(256), 0, stream,
                       seg, row_ptr, hidden, hb, n, P, total25);
    hipLaunchKernelGGL(gat_agg_kernel, dim3((n + 3) / 4), dim3(256), 0, stream,
                       hidden, W, nbr, row_ptr, hb, out, n, P);
}

// Round 3
// 128.359 us; speedup vs baseline: 1.0729x; 1.0729x over previous
//
#include <hip/hip_runtime.h>
#include <math.h>

#define D 100
#define NEG_SLOPE 0.2f
#define CHUNK 16
#define ROWU 52          // uints per packed-f16 row, padded 50->52 for 16B align
#define NPB 2            // nodes (waves) per block — R3: was 4; finer retirement

// compiler-only memory barrier (validated R17: same-wave LDS is pipe-ordered,
// no lgkmcnt(0) drain needed; this only stops compiler reordering)
#define COMPILER_FENCE() asm volatile("" ::: "memory")

typedef _Float16 f16x2 __attribute__((ext_vector_type(2)));
union U32H2 { unsigned int u; f16x2 h; };

__device__ __forceinline__ unsigned int pkh2(float x, float y) {
    U32H2 c; c.h.x = (_Float16)x; c.h.y = (_Float16)y; return c.u;
}

// 2-wide f16 dot + fp32 accumulate: v_dot2_f32_f16
__device__ __forceinline__ float dot2u(unsigned int au, unsigned int xu, float acc) {
#if __has_builtin(__builtin_amdgcn_fdot2)
    U32H2 a, x; a.u = au; x.u = xu;
    return __builtin_amdgcn_fdot2(a.h, x.h, acc, false);
#else
    U32H2 a, x; a.u = au; x.u = xu;
    return acc + (float)a.h.x * (float)x.h.x + (float)a.h.y * (float)x.h.y;
#endif
}

// DPP cross-lane (VALU pipe).
template<int CTRL>
__device__ __forceinline__ float dppf(float x) {
    return __uint_as_float((unsigned)__builtin_amdgcn_update_dpp(
        0, (int)__float_as_uint(x), CTRL, 0xF, 0xF, true));
}
__device__ __forceinline__ float red16_max(float x) {
    x = fmaxf(x, dppf<0xB1>(x));    // quad_perm xor1
    x = fmaxf(x, dppf<0x4E>(x));    // quad_perm xor2
    x = fmaxf(x, dppf<0x124>(x));   // row_ror:4
    x = fmaxf(x, dppf<0x128>(x));   // row_ror:8
    return x;
}
__device__ __forceinline__ float red16_sum(float x) {
    x += dppf<0xB1>(x);
    x += dppf<0x4E>(x);
    x += dppf<0x124>(x);
    x += dppf<0x128>(x);
    return x;
}

// Fused prep: t < P: row_ptr boundary scatter; t < total25: fp32 -> f16 pack.
__global__ void prep_kernel(const int* __restrict__ seg,
                            int* __restrict__ row_ptr,
                            const float* __restrict__ hidden,
                            unsigned int* __restrict__ hb,
                            int n, int P, int total25)
{
    int t = blockIdx.x * blockDim.x + threadIdx.x;
    if (t < P) {
        int s0 = seg[t];
        if (t == 0)
            for (int v = 0; v <= s0; v++) row_ptr[v] = 0;
        int s1 = (t + 1 < P) ? seg[t + 1] : n;
        for (int v = s0 + 1; v <= s1; v++) row_ptr[v] = t + 1;
    }
    if (t < total25) {
        int node = t / 25, k = t - node * 25;   // 25 float4-groups per row
        float4 f = ((const float4*)hidden)[t];
        *(uint2*)&hb[node * ROWU + 2 * k] =
            make_uint2(pkh2(f.x, f.y), pkh2(f.z, f.w));
    }
}

// One wave per node. R3: back to the proven CHUNK=16 / 4-lanes-per-pair
// structure (R2's CHUNK=32 halved occupancy via 28KB LDS and regressed 20%;
// its dur~1/occupancy scaling showed throughput ∝ resident waves). Lever this
// round: 128-thread blocks (2 nodes instead of 4) — halves the LDS+slot
// hostage effect of one slow (high-degree) wave in a block and doubles
// retirement granularity, same 32-wave/CU ceiling (16 wg x 2 waves).
// R1 lesson kept: no register prefetch (neutral, TLP hides gather latency);
// direct masked nbr load instead of preN+shfl.
__launch_bounds__(64 * NPB, 8)
__global__ void gat_agg_kernel(const float* __restrict__ hidden,
                               const float* __restrict__ W,
                               const int* __restrict__ nbr,
                               const int* __restrict__ row_ptr,
                               const unsigned int* __restrict__ hb,
                               float* __restrict__ out,
                               int n, int P)
{
    __shared__ __align__(16) unsigned int s_hwp[NPB][ROWU];         // 0.42 KB
    __shared__ __align__(16) unsigned int s_rows[NPB][CHUNK][ROWU]; // 6.7 KB
    __shared__ __align__(16) float        s_e[NPB][CHUNK];          // 0.13 KB

    const int lane = threadIdx.x & 63;
    const int wid  = threadIdx.x >> 6;
    const int v    = blockIdx.x * NPB + wid;
    if (v >= n) return;          // wave-uniform exit; no block barriers used

    // hw[d] = hidden[v][d] * W[d] (fp32 product, f16-packed into LDS)
    if (lane < 50) {
        float2 h2 = ((const float2*)(hidden + (long)v * D))[lane];
        float2 w2 = ((const float2*)W)[lane];
        s_hwp[wid][lane] = pkh2(h2.x * w2.x, h2.y * w2.y);
    }
    COMPILER_FENCE();

    const int start = row_ptr[v];
    const int end   = row_ptr[v + 1];

    if (end <= start) {          // empty segment: zeros (matches reference)
        if (lane < D / 2)
            ((float2*)(out + (long)v * D))[lane] = make_float2(0.f, 0.f);
        return;
    }

    const int q  = lane >> 4;    // quarter 0..3: uint4s q*3..q*3+2 (+tail on q0)
    const int jl = lane & 15;    // pair slot within the 16-chunk
    const int t0 = q * 3;

    // hoist hw fragment into registers (loop-invariant; 14 regs)
    const uint4* hwq = ((const uint4*)&s_hwp[wid][0]) + t0;
    const uint4 a0 = hwq[0], a1 = hwq[1], a2 = hwq[2];
    uint2 at = make_uint2(0u, 0u);
    if (q == 0) at = *(const uint2*)&s_hwp[wid][48];

    float m = -INFINITY, z = 0.f;
    float accx = 0.f, accy = 0.f;

    for (int c = start; c < end; c += CHUNK) {
        const int  cnt = min(CHUNK, end - c);
        const bool pv  = jl < cnt;

        // neighbor index: coalesced masked load. invalid lanes use row 0
        // (finite, in-bounds, L1-hot); e=0 masks them later.
        const int nbv = pv ? nbr[c + jl] : 0;
        const uint4* row16 = ((const uint4*)hb) + nbv * (ROWU / 4) + t0;

        // ---- Phase A: f16 quarter-row gather (3x16B + 8B tail), fdot2 ----
        uint4 x0 = row16[0], x1 = row16[1], x2 = row16[2];
        uint2 xt = make_uint2(0u, 0u);
        if (q == 0) xt = *(const uint2*)&hb[nbv * ROWU + 48];   // dims 96..99

        float p0 = 0.f, p1 = 0.f, p2 = 0.f, p3 = 0.f;
        p0 = dot2u(a0.x, x0.x, p0);  p1 = dot2u(a0.y, x0.y, p1);
        p2 = dot2u(a0.z, x0.z, p2);  p3 = dot2u(a0.w, x0.w, p3);
        p0 = dot2u(a1.x, x1.x, p0);  p1 = dot2u(a1.y, x1.y, p1);
        p2 = dot2u(a1.z, x1.z, p2);  p3 = dot2u(a1.w, x1.w, p3);
        p0 = dot2u(a2.x, x2.x, p0);  p1 = dot2u(a2.y, x2.y, p1);
        p2 = dot2u(a2.z, x2.z, p2);  p3 = dot2u(a2.w, x2.w, p3);
        if (q == 0) {
            p0 = dot2u(at.x, xt.x, p0);
            p1 = dot2u(at.y, xt.y, p1);
        }

        // stage raw f16 row to LDS (16B-aligned: ROWU*4 = 208 = 13*16)
        uint4* dst16 = ((uint4*)&s_rows[wid][jl][0]) + t0;
        dst16[0] = x0; dst16[1] = x1; dst16[2] = x2;
        if (q == 0) *(uint2*)&s_rows[wid][jl][48] = xt;

        float part = (p0 + p1) + (p2 + p3);
        part += __shfl_xor(part, 16, 64);    // combine quarters (LDS pipe)
        part += __shfl_xor(part, 32, 64);
        const float s = pv ? (part >= 0.f ? part : NEG_SLOPE * part)
                           : -INFINITY;

        // ---- online softmax: DPP trees within each 16-group ----
        const float m_new = fmaxf(m, red16_max(s));
        const float scale = __expf(m - m_new);         // first chunk: 0
        const float e     = pv ? __expf(s - m_new) : 0.f;
        z = z * scale + red16_sum(e);
        accx *= scale; accy *= scale;

        if (lane < CHUNK) s_e[wid][lane] = e;          // q0 lanes: jl == lane
        COMPILER_FENCE();        // order stores before phase-B reads (same wave)

        // ---- Phase B: lane-per-dim accumulate; v_fma_mix form ----
        const int cnt4 = (cnt + 3) & ~3;               // <= 16
        if (lane < D / 2) {
            for (int j0 = 0; j0 < cnt4; j0 += 4) {
                const float4 ev = *(const float4*)&s_e[wid][j0];  // broadcast
                U32H2 u0, u1, u2, u3;
                u0.u = s_rows[wid][j0    ][lane];
                u1.u = s_rows[wid][j0 + 1][lane];
                u2.u = s_rows[wid][j0 + 2][lane];
                u3.u = s_rows[wid][j0 + 3][lane];
                accx = fmaf((float)u0.h.x, ev.x, accx);
                accy = fmaf((float)u0.h.y, ev.x, accy);
                accx = fmaf((float)u1.h.x, ev.y, accx);
                accy = fmaf((float)u1.h.y, ev.y, accy);
                accx = fmaf((float)u2.h.x, ev.z, accx);
                accy = fmaf((float)u2.h.y, ev.z, accy);
                accx = fmaf((float)u3.h.x, ev.w, accx);
                accy = fmaf((float)u3.h.y, ev.w, accy);
            }
        }
        COMPILER_FENCE();        // phase-B reads before next chunk's stores
        m = m_new;
    }

    if (lane < D / 2) {
        const float inv = 1.f / z;
        ((float2*)(out + (long)v * D))[lane] = make_float2(accx * inv, accy * inv);
    }
}

extern "C" void kernel_launch(void* const* d_in, const int* in_sizes, int n_in,
                              void* d_out, int out_size, void* d_ws, size_t ws_size,
                              hipStream_t stream) {
    const float* hidden = (const float*)d_in[0];
    const float* W      = (const float*)d_in[1];
    const int*   seg    = (const int*)d_in[2];
    const int*   nbr    = (const int*)d_in[3];
    float*       out    = (float*)d_out;

    const int Ddim = in_sizes[1];           // 100
    const int n    = in_sizes[0] / Ddim;    // 50000
    const int P    = in_sizes[2];           // ~1.3M pairs

    // ws layout: row_ptr (n+1 ints) | hb (n*ROWU uints, 256B-aligned)
    int* row_ptr = (int*)d_ws;
    size_t hb_off = (((size_t)(n + 1) * 4) + 255) & ~(size_t)255;
    unsigned int* hb = (unsigned int*)((char*)d_ws + hb_off);

    const int total25 = n * 25;             // float4-groups in hidden
    const int tmax    = (P > total25) ? P : total25;
    hipLaunchKernelGGL(prep_kernel, dim3((tmax + 255) / 256), dim3(256), 0, stream,
                       seg, row_ptr, hidden, hb, n, P, total25);
    hipLaunchKernelGGL(gat_agg_kernel, dim3((n + NPB - 1) / NPB), dim3(64 * NPB),
                       0, stream, hidden, W, nbr, row_ptr, hb, out, n, P);
}